// Round 1
// baseline (390.927 us; speedup 1.0000x reference)
//
#include <hip/hip_runtime.h>
#include <math.h>

#define B_DIM 2
#define S_DIM 2048
#define D_DIM 1024
#define H_NUM 16
#define DH    64
#define M_DIM (B_DIM * S_DIM) /* 4096 */

typedef __attribute__((ext_vector_type(8))) short short8;
typedef __attribute__((ext_vector_type(4))) float float4v;
typedef __attribute__((ext_vector_type(4))) unsigned short ushort4v;
typedef unsigned short ushort;

static __device__ __forceinline__ ushort f2bf(float f) {
    unsigned u = __float_as_uint(f);
    u += 0x7fffu + ((u >> 16) & 1u);
    return (ushort)(u >> 16);
}

static __device__ __forceinline__ float fexp2(float x) {
#if __has_builtin(__builtin_amdgcn_exp2f)
    return __builtin_amdgcn_exp2f(x);
#else
    return exp2f(x);
#endif
}

static __device__ __forceinline__ void gload_lds16(const void* g, void* l) {
    __builtin_amdgcn_global_load_lds(
        (const __attribute__((address_space(1))) void*)g,
        (__attribute__((address_space(3))) void*)l, 16, 0, 0);
}

// ---------------------------------------------------------------------------
// fp32 -> bf16 cast, float4/ushort4 vectorized. n4 = element count / 4.
// ---------------------------------------------------------------------------
__global__ __launch_bounds__(256)
void cast_f32_bf16(const float* __restrict__ s, ushort* __restrict__ d, int n4)
{
    const int i = blockIdx.x * 256 + threadIdx.x;
    if (i < n4) {
        const float4 v = ((const float4*)s)[i];
        ushort4v o;
        o[0] = f2bf(v.x); o[1] = f2bf(v.y); o[2] = f2bf(v.z); o[3] = f2bf(v.w);
        ((ushort4v*)d)[i] = o;
    }
}

// ---------------------------------------------------------------------------
// bf16 MFMA GEMM, m97 structure: 128x128 tile, BK=32, global_load_lds w=16,
// 4 waves in 2x2, each wave 64x64 via 4x4 grid of 16x16x32 MFMAs.
// A:[M=4096, K=1024] bf16 row-major. B:[N, K=1024] bf16 row-major.
// mode 0 (N=3072, fused QKV): n>>10 selects dst: 0->Qh [B,H,S,Dh]
//        (PRE-SCALED by 0.125*log2e for base-2 online softmax),
//        1->Kh [B,H,S,Dh], 2->Vt [B,H,Dh,S]; all bf16.
// mode 1 (N=1024, out proj): fp32 out[m*1024+n] = acc + bias[n].
// ---------------------------------------------------------------------------
__global__ __launch_bounds__(256)
void gemm_bf16(const ushort* __restrict__ A, const ushort* __restrict__ B,
               ushort* __restrict__ Qh, ushort* __restrict__ Kh,
               ushort* __restrict__ Vt, float* __restrict__ Of,
               const float* __restrict__ bias, int mode)
{
    __shared__ ushort Asm[128 * 32];   // [row][k], 64B rows, lane-order (no pad!)
    __shared__ ushort Bsm[128 * 32];

    const int K  = 1024;
    const int n0 = blockIdx.x * 128;
    const int m0 = blockIdx.y * 128;
    const int t    = threadIdx.x;
    const int w    = t >> 6;
    const int lane = t & 63;
    const int n    = lane & 15;
    const int quad = lane >> 4;
    const int wm = w >> 1, wn = w & 1;

    // staging addresses: load i covers rows w*32+i*16 + (lane>>2), kchunk lane&3
    const int srow = w * 32 + (lane >> 2);
    const int skel = (lane & 3) * 8;

    float4v acc[4][4];
#pragma unroll
    for (int mt = 0; mt < 4; ++mt)
#pragma unroll
        for (int nt = 0; nt < 4; ++nt) acc[mt][nt] = (float4v){0.f, 0.f, 0.f, 0.f};

    for (int kt = 0; kt < K; kt += 32) {
#pragma unroll
        for (int i = 0; i < 2; ++i) {
            gload_lds16(&A[(size_t)(m0 + srow + i * 16) * K + kt + skel],
                        &Asm[(w * 2 + i) * 512]);
            gload_lds16(&B[(size_t)(n0 + srow + i * 16) * K + kt + skel],
                        &Bsm[(w * 2 + i) * 512]);
        }
        __syncthreads();

        short8 af[4], bfr[4];
#pragma unroll
        for (int mt = 0; mt < 4; ++mt)
            af[mt] = *(const short8*)&Asm[(wm * 64 + mt * 16 + n) * 32 + quad * 8];
#pragma unroll
        for (int nt = 0; nt < 4; ++nt)
            bfr[nt] = *(const short8*)&Bsm[(wn * 64 + nt * 16 + n) * 32 + quad * 8];

#pragma unroll
        for (int mt = 0; mt < 4; ++mt)
#pragma unroll
            for (int nt = 0; nt < 4; ++nt)
                acc[mt][nt] = __builtin_amdgcn_mfma_f32_16x16x32_bf16(
                    af[mt], bfr[nt], acc[mt][nt], 0, 0, 0);
        __syncthreads();
    }

    if (mode == 0) {
        const int wid = n0 >> 10;           // 0=Q 1=K 2=V (constant per block)
        ushort* dstQK = (wid == 0) ? Qh : Kh;
        // Q is pre-scaled by softmax scale * log2(e) so attention can use exp2
        const float qs = (wid == 0) ? 0.1803368801f : 1.0f;
#pragma unroll
        for (int mt = 0; mt < 4; ++mt) {
            const int m = m0 + wm * 64 + mt * 16 + quad * 4;   // +r
            const int b = m >> 11, s = m & (S_DIM - 1);
#pragma unroll
            for (int nt = 0; nt < 4; ++nt) {
                const int ng = (n0 & 1023) + wn * 64 + nt * 16 + n;
                const int h = ng >> 6, d = ng & 63;
                const int bh = b * H_NUM + h;
                if (wid < 2) {
#pragma unroll
                    for (int r = 0; r < 4; ++r)
                        dstQK[(((size_t)bh * S_DIM + s + r) << 6) + d] =
                            f2bf(acc[mt][nt][r] * qs);
                } else {
                    ushort4v p;
#pragma unroll
                    for (int r = 0; r < 4; ++r) p[r] = f2bf(acc[mt][nt][r]);
                    *(ushort4v*)&Vt[(((size_t)bh * DH + d) << 11) + s] = p;
                }
            }
        }
    } else {
#pragma unroll
        for (int mt = 0; mt < 4; ++mt) {
            const int m = m0 + wm * 64 + mt * 16 + quad * 4;
#pragma unroll
            for (int nt = 0; nt < 4; ++nt) {
                const int ng = n0 + wn * 64 + nt * 16 + n;
                const float bv = bias[ng];
#pragma unroll
                for (int r = 0; r < 4; ++r)
                    Of[(size_t)(m + r) * D_DIM + ng] = acc[mt][nt][r] + bv;
            }
        }
    }
}

// ---------------------------------------------------------------------------
// MFMA flash attention. 16 query rows per wave (was 32): 4096 waves = 1024
// blocks -> 4 blocks/CU -> 16 waves/CU (50% occupancy, was 25%). Q comes in
// pre-scaled by 0.125*log2e, softmax runs in base-2 (exp2).
// ---------------------------------------------------------------------------
#define P_LD 72

__global__ __launch_bounds__(256)
void attn_mfma(const ushort* __restrict__ Qh, const ushort* __restrict__ Kh,
               const ushort* __restrict__ Vt, ushort* __restrict__ Yh)
{
    __shared__ short Pb[4][16][P_LD];

    const int w    = threadIdx.x >> 6;
    const int lane = threadIdx.x & 63;
    const int n    = lane & 15;
    const int quad = lane >> 4;

    const int wave_id = blockIdx.x * 4 + w;
    const int bh    = wave_id >> 7;                 // 128 waves per (b,h)
    const int qbase = (wave_id & 127) * 16;
    const int b     = bh >> 4;
    const int h     = bh & (H_NUM - 1);

    const ushort* Qb = Qh + (((size_t)bh * S_DIM) << 6);
    const ushort* Kb = Kh + (((size_t)bh * S_DIM) << 6);
    const ushort* Vb = Vt + (((size_t)bh * DH) << 11);

    short8 qa[2];
#pragma unroll
    for (int kc = 0; kc < 2; ++kc)
        qa[kc] = *(const short8*)&Qb[((size_t)(qbase + n) << 6) + kc * 32 + quad * 8];

    float4v O[4];
    float   mrow[4], lrow[4];
#pragma unroll
    for (int nt = 0; nt < 4; ++nt) O[nt] = (float4v){0.f, 0.f, 0.f, 0.f};
#pragma unroll
    for (int r = 0; r < 4; ++r) { mrow[r] = -1e30f; lrow[r] = 0.f; }

    for (int kb = 0; kb < S_DIM / 64; ++kb) {
        const int key0 = kb * 64;
        short8 kf[4][2];
#pragma unroll
        for (int ct = 0; ct < 4; ++ct)
#pragma unroll
            for (int kc = 0; kc < 2; ++kc)
                kf[ct][kc] = *(const short8*)&Kb[((size_t)(key0 + ct * 16 + n) << 6) + kc * 32 + quad * 8];

        float4v s[4];
#pragma unroll
        for (int ct = 0; ct < 4; ++ct) {
            float4v a = (float4v){0.f, 0.f, 0.f, 0.f};
            a = __builtin_amdgcn_mfma_f32_16x16x32_bf16(qa[0], kf[ct][0], a, 0, 0, 0);
            a = __builtin_amdgcn_mfma_f32_16x16x32_bf16(qa[1], kf[ct][1], a, 0, 0, 0);
            s[ct] = a;
        }

        short8 vf[4][2];
#pragma unroll
        for (int nt = 0; nt < 4; ++nt)
#pragma unroll
            for (int kc = 0; kc < 2; ++kc)
                vf[nt][kc] = *(const short8*)&Vb[((size_t)(nt * 16 + n) << 11) + key0 + kc * 32 + quad * 8];

#pragma unroll
        for (int r = 0; r < 4; ++r) {
            const float a0 = s[0][r];
            const float a1 = s[1][r];
            const float a2 = s[2][r];
            const float a3 = s[3][r];
            float cm = fmaxf(fmaxf(a0, a1), fmaxf(a2, a3));
            cm = fmaxf(cm, __shfl_xor(cm, 1, 64));
            cm = fmaxf(cm, __shfl_xor(cm, 2, 64));
            cm = fmaxf(cm, __shfl_xor(cm, 4, 64));
            cm = fmaxf(cm, __shfl_xor(cm, 8, 64));
            const float mnew  = fmaxf(mrow[r], cm);
            const float alpha = fexp2(mrow[r] - mnew);
            mrow[r] = mnew;
            const float p0 = fexp2(a0 - mnew);
            const float p1 = fexp2(a1 - mnew);
            const float p2 = fexp2(a2 - mnew);
            const float p3 = fexp2(a3 - mnew);
            lrow[r] = lrow[r] * alpha + (p0 + p1 + p2 + p3);
#pragma unroll
            for (int nt = 0; nt < 4; ++nt) O[nt][r] *= alpha;
            const int prow = quad * 4 + r;
            Pb[w][prow][0 * 16 + n] = (short)f2bf(p0);
            Pb[w][prow][1 * 16 + n] = (short)f2bf(p1);
            Pb[w][prow][2 * 16 + n] = (short)f2bf(p2);
            Pb[w][prow][3 * 16 + n] = (short)f2bf(p3);
        }
        const short8 pa0 = *(const short8*)&Pb[w][n][quad * 8];
        const short8 pa1 = *(const short8*)&Pb[w][n][32 + quad * 8];
#pragma unroll
        for (int nt = 0; nt < 4; ++nt) {
            O[nt] = __builtin_amdgcn_mfma_f32_16x16x32_bf16(pa0, vf[nt][0], O[nt], 0, 0, 0);
            O[nt] = __builtin_amdgcn_mfma_f32_16x16x32_bf16(pa1, vf[nt][1], O[nt], 0, 0, 0);
        }
    }

    float linv[4];
#pragma unroll
    for (int r = 0; r < 4; ++r) {
        float ls = lrow[r];
        ls += __shfl_xor(ls, 1, 64);
        ls += __shfl_xor(ls, 2, 64);
        ls += __shfl_xor(ls, 4, 64);
        ls += __shfl_xor(ls, 8, 64);
        linv[r] = 1.f / ls;
    }
#pragma unroll
    for (int nt = 0; nt < 4; ++nt)
#pragma unroll
        for (int r = 0; r < 4; ++r) {
            const int q = qbase + quad * 4 + r;
            Yh[((size_t)(b * S_DIM + q) << 10) + h * DH + nt * 16 + n] =
                f2bf(O[nt][r] * linv[r]);
        }
}

// ---------------------------------------------------------------------------
extern "C" void kernel_launch(void* const* d_in, const int* in_sizes, int n_in,
                              void* d_out, int out_size, void* d_ws, size_t ws_size,
                              hipStream_t stream)
{
    const float* x  = (const float*)d_in[0];
    const float* wq = (const float*)d_in[1];
    const float* wk = (const float*)d_in[2];
    const float* wv = (const float*)d_in[3];
    const float* wo = (const float*)d_in[4];
    const float* bo = (const float*)d_in[5];
    float* out = (float*)d_out;

    const size_t MD = (size_t)M_DIM * D_DIM;      // 4M elements
    const size_t WD = (size_t)D_DIM * D_DIM;      // 1M elements
    ushort* xh  = (ushort*)d_ws;      // 8 MB  [M,K] bf16
    ushort* Wh  = xh + MD;            // 6 MB  [3072,1024] bf16 (wq|wk|wv)
    ushort* Woh = Wh + 3 * WD;        // 2 MB  [1024,1024] bf16
    ushort* Qh  = Woh + WD;           // 8 MB  [B,H,S,Dh] bf16 (pre-scaled)
    ushort* Kh  = Qh + MD;            // 8 MB  [B,H,S,Dh] bf16
    ushort* Vt  = Kh + MD;            // 8 MB  [B,H,Dh,S] bf16
    ushort* Yh  = Vt + MD;            // 8 MB  [M,D] bf16
    if (ws_size < 48u * 1024u * 1024u) return;

    dim3 blk(256);
    cast_f32_bf16<<<dim3((int)(MD / 4 / 256)), blk, 0, stream>>>(x,  xh,           (int)(MD / 4));
    cast_f32_bf16<<<dim3((int)(WD / 4 / 256)), blk, 0, stream>>>(wq, Wh,           (int)(WD / 4));
    cast_f32_bf16<<<dim3((int)(WD / 4 / 256)), blk, 0, stream>>>(wk, Wh + WD,      (int)(WD / 4));
    cast_f32_bf16<<<dim3((int)(WD / 4 / 256)), blk, 0, stream>>>(wv, Wh + 2 * WD,  (int)(WD / 4));
    cast_f32_bf16<<<dim3((int)(WD / 4 / 256)), blk, 0, stream>>>(wo, Woh,          (int)(WD / 4));

    gemm_bf16<<<dim3(24, 32), blk, 0, stream>>>(xh, Wh, Qh, Kh, Vt, nullptr, nullptr, 0);
    attn_mfma<<<dim3(1024), blk, 0, stream>>>(Qh, Kh, Vt, Yh);
    gemm_bf16<<<dim3(8, 32), blk, 0, stream>>>(Yh, Woh, nullptr, nullptr, nullptr, out, bo, 1);
}

// Round 2
// 263.515 us; speedup vs baseline: 1.4835x; 1.4835x over previous
//
#include <hip/hip_runtime.h>
#include <math.h>

#define B_DIM 2
#define S_DIM 2048
#define D_DIM 1024
#define H_NUM 16
#define DH    64
#define M_DIM (B_DIM * S_DIM) /* 4096 */

typedef __attribute__((ext_vector_type(8))) short short8;
typedef __attribute__((ext_vector_type(4))) float float4v;
typedef __attribute__((ext_vector_type(4))) unsigned short ushort4v;
typedef unsigned short ushort;

static __device__ __forceinline__ ushort f2bf(float f) {
    unsigned u = __float_as_uint(f);
    u += 0x7fffu + ((u >> 16) & 1u);
    return (ushort)(u >> 16);
}

static __device__ __forceinline__ float fexp2(float x) {
#if __has_builtin(__builtin_amdgcn_exp2f)
    return __builtin_amdgcn_exp2f(x);
#else
    return exp2f(x);
#endif
}

static __device__ __forceinline__ void gload_lds16(const void* g, void* l) {
    __builtin_amdgcn_global_load_lds(
        (const __attribute__((address_space(1))) void*)g,
        (__attribute__((address_space(3))) void*)l, 16, 0, 0);
}

// ---------------------------------------------------------------------------
// fp32 -> bf16 cast, float4/ushort4 vectorized. n4 = element count / 4.
// ---------------------------------------------------------------------------
__global__ __launch_bounds__(256)
void cast_f32_bf16(const float* __restrict__ s, ushort* __restrict__ d, int n4)
{
    const int i = blockIdx.x * 256 + threadIdx.x;
    if (i < n4) {
        const float4 v = ((const float4*)s)[i];
        ushort4v o;
        o[0] = f2bf(v.x); o[1] = f2bf(v.y); o[2] = f2bf(v.z); o[3] = f2bf(v.w);
        ((ushort4v*)d)[i] = o;
    }
}

// ---------------------------------------------------------------------------
// bf16 MFMA GEMM, m97 structure: 128x128 tile, BK=32, global_load_lds w=16,
// 4 waves in 2x2, each wave 64x64 via 4x4 grid of 16x16x32 MFMAs.
// A:[M=4096, K=1024] bf16 row-major. B:[N, K=1024] bf16 row-major.
// mode 0 (N=3072, fused QKV): n>>10 selects dst: 0->Qh [B,H,S,Dh]
//        (PRE-SCALED by 0.125*log2e for base-2 online softmax),
//        1->Kh [B,H,S,Dh], 2->Vt [B,H,Dh,S]; all bf16.
// mode 1 (N=1024, out proj): fp32 out[m*1024+n] = acc + bias[n].
// ---------------------------------------------------------------------------
__global__ __launch_bounds__(256)
void gemm_bf16(const ushort* __restrict__ A, const ushort* __restrict__ B,
               ushort* __restrict__ Qh, ushort* __restrict__ Kh,
               ushort* __restrict__ Vt, float* __restrict__ Of,
               const float* __restrict__ bias, int mode)
{
    __shared__ ushort Asm[128 * 32];   // [row][k], 64B rows, lane-order (no pad!)
    __shared__ ushort Bsm[128 * 32];

    const int K  = 1024;
    const int n0 = blockIdx.x * 128;
    const int m0 = blockIdx.y * 128;
    const int t    = threadIdx.x;
    const int w    = t >> 6;
    const int lane = t & 63;
    const int n    = lane & 15;
    const int quad = lane >> 4;
    const int wm = w >> 1, wn = w & 1;

    // staging addresses: load i covers rows w*32+i*16 + (lane>>2), kchunk lane&3
    const int srow = w * 32 + (lane >> 2);
    const int skel = (lane & 3) * 8;

    float4v acc[4][4];
#pragma unroll
    for (int mt = 0; mt < 4; ++mt)
#pragma unroll
        for (int nt = 0; nt < 4; ++nt) acc[mt][nt] = (float4v){0.f, 0.f, 0.f, 0.f};

    for (int kt = 0; kt < K; kt += 32) {
#pragma unroll
        for (int i = 0; i < 2; ++i) {
            gload_lds16(&A[(size_t)(m0 + srow + i * 16) * K + kt + skel],
                        &Asm[(w * 2 + i) * 512]);
            gload_lds16(&B[(size_t)(n0 + srow + i * 16) * K + kt + skel],
                        &Bsm[(w * 2 + i) * 512]);
        }
        __syncthreads();

        short8 af[4], bfr[4];
#pragma unroll
        for (int mt = 0; mt < 4; ++mt)
            af[mt] = *(const short8*)&Asm[(wm * 64 + mt * 16 + n) * 32 + quad * 8];
#pragma unroll
        for (int nt = 0; nt < 4; ++nt)
            bfr[nt] = *(const short8*)&Bsm[(wn * 64 + nt * 16 + n) * 32 + quad * 8];

#pragma unroll
        for (int mt = 0; mt < 4; ++mt)
#pragma unroll
            for (int nt = 0; nt < 4; ++nt)
                acc[mt][nt] = __builtin_amdgcn_mfma_f32_16x16x32_bf16(
                    af[mt], bfr[nt], acc[mt][nt], 0, 0, 0);
        __syncthreads();
    }

    if (mode == 0) {
        const int wid = n0 >> 10;           // 0=Q 1=K 2=V (constant per block)
        ushort* dstQK = (wid == 0) ? Qh : Kh;
        // Q is pre-scaled by softmax scale * log2(e) so attention can use exp2
        const float qs = (wid == 0) ? 0.1803368801f : 1.0f;
#pragma unroll
        for (int mt = 0; mt < 4; ++mt) {
            const int m = m0 + wm * 64 + mt * 16 + quad * 4;   // +r
            const int b = m >> 11, s = m & (S_DIM - 1);
#pragma unroll
            for (int nt = 0; nt < 4; ++nt) {
                const int ng = (n0 & 1023) + wn * 64 + nt * 16 + n;
                const int h = ng >> 6, d = ng & 63;
                const int bh = b * H_NUM + h;
                if (wid < 2) {
#pragma unroll
                    for (int r = 0; r < 4; ++r)
                        dstQK[(((size_t)bh * S_DIM + s + r) << 6) + d] =
                            f2bf(acc[mt][nt][r] * qs);
                } else {
                    ushort4v p;
#pragma unroll
                    for (int r = 0; r < 4; ++r) p[r] = f2bf(acc[mt][nt][r]);
                    *(ushort4v*)&Vt[(((size_t)bh * DH + d) << 11) + s] = p;
                }
            }
        }
    } else {
#pragma unroll
        for (int mt = 0; mt < 4; ++mt) {
            const int m = m0 + wm * 64 + mt * 16 + quad * 4;
#pragma unroll
            for (int nt = 0; nt < 4; ++nt) {
                const int ng = n0 + wn * 64 + nt * 16 + n;
                const float bv = bias[ng];
#pragma unroll
                for (int r = 0; r < 4; ++r)
                    Of[(size_t)(m + r) * D_DIM + ng] = acc[mt][nt][r] + bv;
            }
        }
    }
}

// ---------------------------------------------------------------------------
// MFMA flash attention, round-0 geometry (32 q-rows/wave, 512 blocks) +
// block-shared LDS K/V staging. All 4 waves of a block share one (b,h);
// previously each wave loaded identical K/V fragments from global (the
// measured per-wave critical path). Now: 64x64 K-tile and V-tile staged
// once per block via global_load_lds (4 instr/wave/kb instead of 16 global
// reads), double-buffered, ONE barrier per kb so next-tile loads fly under
// current-tile compute. LDS granule-XOR swizzle (g ^= row&7), pre-applied
// on the global source address (gload_lds dst must stay linear), makes the
// ds_read_b128 fragment reads full-bank-spread.
// Softmax is base-2; Q arrives pre-scaled by 0.125*log2e.
// ---------------------------------------------------------------------------
#define P_LD 72

__global__ __launch_bounds__(256)
void attn_mfma(const ushort* __restrict__ Qh, const ushort* __restrict__ Kh,
               const ushort* __restrict__ Vt, ushort* __restrict__ Yh)
{
    __shared__ ushort Ksm[2][64 * 64];   // [buf][row(key) 64][col(d) 64] swizzled
    __shared__ ushort Vsm[2][64 * 64];   // [buf][row(d) 64][col(key) 64] swizzled
    __shared__ short  Pb[4][2][16][P_LD];

    const int w    = threadIdx.x >> 6;
    const int lane = threadIdx.x & 63;
    const int n    = lane & 15;
    const int quad = lane >> 4;

    const int wave_id = blockIdx.x * 4 + w;
    const int bh    = wave_id >> 6;          // all 4 waves of a block: same bh
    const int qbase = (wave_id & 63) * 32;
    const int b     = bh >> 4;
    const int h     = bh & (H_NUM - 1);

    const ushort* Qb = Qh + (((size_t)bh * S_DIM) << 6);
    const ushort* Kb = Kh + (((size_t)bh * S_DIM) << 6);
    const ushort* Vb = Vt + (((size_t)bh * DH) << 11);

    // staging lane constants: lane l covers row sub-index l>>3 (rows are
    // 8-aligned per load), 16B granule (l&7); source granule pre-swizzled.
    const int l8 = lane >> 3;            // 0..7
    const int sg = (lane & 7) ^ l8;      // swizzled source granule 0..7

    short8 qa[2][2];
#pragma unroll
    for (int mt = 0; mt < 2; ++mt)
#pragma unroll
        for (int kc = 0; kc < 2; ++kc)
            qa[mt][kc] = *(const short8*)&Qb[((size_t)(qbase + mt * 16 + n) << 6) + kc * 32 + quad * 8];

    float4v O[2][4];
    float   mrow[2][4], lrow[2][4];
#pragma unroll
    for (int mt = 0; mt < 2; ++mt) {
#pragma unroll
        for (int nt = 0; nt < 4; ++nt) O[mt][nt] = (float4v){0.f, 0.f, 0.f, 0.f};
#pragma unroll
        for (int r = 0; r < 4; ++r) { mrow[mt][r] = -1e30f; lrow[mt][r] = 0.f; }
    }

    // fragment-read LDS offsets (ushort units): row rr, granule g -> 
    //   rr*64 + ((g ^ (rr&7)) * 8);  rr&7 == n&7 for rr = xt*16 + n.
    const int fswz[2] = { ((0 * 4 + quad) ^ (n & 7)) * 8,
                          ((1 * 4 + quad) ^ (n & 7)) * 8 };

    // prologue: stage tile 0 into buffer 0
#pragma unroll
    for (int i = 0; i < 2; ++i) {
        gload_lds16(&Kb[(size_t)(w * 16 + i * 8 + l8) * 64 + sg * 8],
                    &Ksm[0][(w * 16 + i * 8) * 64]);
        gload_lds16(&Vb[(size_t)(w * 16 + i * 8 + l8) * 2048 + sg * 8],
                    &Vsm[0][(w * 16 + i * 8) * 64]);
    }

    for (int kb = 0; kb < S_DIM / 64; ++kb) {
        __syncthreads();   // stage(kb) complete (vmcnt drained at barrier);
                           // also: everyone done reading buf cur^1 (2 its ago)
        const int cur = kb & 1;
        if (kb + 1 < S_DIM / 64) {
            const int key1 = (kb + 1) * 64;
            const int nxt  = cur ^ 1;
#pragma unroll
            for (int i = 0; i < 2; ++i) {
                gload_lds16(&Kb[(size_t)(key1 + w * 16 + i * 8 + l8) * 64 + sg * 8],
                            &Ksm[nxt][(w * 16 + i * 8) * 64]);
                gload_lds16(&Vb[(size_t)(w * 16 + i * 8 + l8) * 2048 + key1 + sg * 8],
                            &Vsm[nxt][(w * 16 + i * 8) * 64]);
            }
        }

        short8 kf[4][2];
#pragma unroll
        for (int ct = 0; ct < 4; ++ct)
#pragma unroll
            for (int kc = 0; kc < 2; ++kc)
                kf[ct][kc] = *(const short8*)&Ksm[cur][(ct * 16 + n) * 64 + fswz[kc]];

        float4v s[2][4];
#pragma unroll
        for (int mt = 0; mt < 2; ++mt)
#pragma unroll
            for (int ct = 0; ct < 4; ++ct) {
                float4v a = (float4v){0.f, 0.f, 0.f, 0.f};
                a = __builtin_amdgcn_mfma_f32_16x16x32_bf16(qa[mt][0], kf[ct][0], a, 0, 0, 0);
                a = __builtin_amdgcn_mfma_f32_16x16x32_bf16(qa[mt][1], kf[ct][1], a, 0, 0, 0);
                s[mt][ct] = a;
            }

        short8 vf[4][2];
#pragma unroll
        for (int nt = 0; nt < 4; ++nt)
#pragma unroll
            for (int kc = 0; kc < 2; ++kc)
                vf[nt][kc] = *(const short8*)&Vsm[cur][(nt * 16 + n) * 64 + fswz[kc]];

#pragma unroll
        for (int mt = 0; mt < 2; ++mt) {
#pragma unroll
            for (int r = 0; r < 4; ++r) {
                const float a0 = s[mt][0][r];
                const float a1 = s[mt][1][r];
                const float a2 = s[mt][2][r];
                const float a3 = s[mt][3][r];
                float cm = fmaxf(fmaxf(a0, a1), fmaxf(a2, a3));
                cm = fmaxf(cm, __shfl_xor(cm, 1, 64));
                cm = fmaxf(cm, __shfl_xor(cm, 2, 64));
                cm = fmaxf(cm, __shfl_xor(cm, 4, 64));
                cm = fmaxf(cm, __shfl_xor(cm, 8, 64));
                const float mnew  = fmaxf(mrow[mt][r], cm);
                const float alpha = fexp2(mrow[mt][r] - mnew);
                mrow[mt][r] = mnew;
                const float p0 = fexp2(a0 - mnew);
                const float p1 = fexp2(a1 - mnew);
                const float p2 = fexp2(a2 - mnew);
                const float p3 = fexp2(a3 - mnew);
                lrow[mt][r] = lrow[mt][r] * alpha + (p0 + p1 + p2 + p3);
#pragma unroll
                for (int nt = 0; nt < 4; ++nt) O[mt][nt][r] *= alpha;
                const int prow = quad * 4 + r;
                Pb[w][mt][prow][0 * 16 + n] = (short)f2bf(p0);
                Pb[w][mt][prow][1 * 16 + n] = (short)f2bf(p1);
                Pb[w][mt][prow][2 * 16 + n] = (short)f2bf(p2);
                Pb[w][mt][prow][3 * 16 + n] = (short)f2bf(p3);
            }
            const short8 pa0 = *(const short8*)&Pb[w][mt][n][quad * 8];
            const short8 pa1 = *(const short8*)&Pb[w][mt][n][32 + quad * 8];
#pragma unroll
            for (int nt = 0; nt < 4; ++nt) {
                O[mt][nt] = __builtin_amdgcn_mfma_f32_16x16x32_bf16(pa0, vf[nt][0], O[mt][nt], 0, 0, 0);
                O[mt][nt] = __builtin_amdgcn_mfma_f32_16x16x32_bf16(pa1, vf[nt][1], O[mt][nt], 0, 0, 0);
            }
        }
    }

#pragma unroll
    for (int mt = 0; mt < 2; ++mt) {
        float linv[4];
#pragma unroll
        for (int r = 0; r < 4; ++r) {
            float ls = lrow[mt][r];
            ls += __shfl_xor(ls, 1, 64);
            ls += __shfl_xor(ls, 2, 64);
            ls += __shfl_xor(ls, 4, 64);
            ls += __shfl_xor(ls, 8, 64);
            linv[r] = 1.f / ls;
        }
#pragma unroll
        for (int nt = 0; nt < 4; ++nt)
#pragma unroll
            for (int r = 0; r < 4; ++r) {
                const int q = qbase + mt * 16 + quad * 4 + r;
                Yh[((size_t)(b * S_DIM + q) << 10) + h * DH + nt * 16 + n] =
                    f2bf(O[mt][nt][r] * linv[r]);
            }
    }
}

// ---------------------------------------------------------------------------
extern "C" void kernel_launch(void* const* d_in, const int* in_sizes, int n_in,
                              void* d_out, int out_size, void* d_ws, size_t ws_size,
                              hipStream_t stream)
{
    const float* x  = (const float*)d_in[0];
    const float* wq = (const float*)d_in[1];
    const float* wk = (const float*)d_in[2];
    const float* wv = (const float*)d_in[3];
    const float* wo = (const float*)d_in[4];
    const float* bo = (const float*)d_in[5];
    float* out = (float*)d_out;

    const size_t MD = (size_t)M_DIM * D_DIM;      // 4M elements
    const size_t WD = (size_t)D_DIM * D_DIM;      // 1M elements
    ushort* xh  = (ushort*)d_ws;      // 8 MB  [M,K] bf16
    ushort* Wh  = xh + MD;            // 6 MB  [3072,1024] bf16 (wq|wk|wv)
    ushort* Woh = Wh + 3 * WD;        // 2 MB  [1024,1024] bf16
    ushort* Qh  = Woh + WD;           // 8 MB  [B,H,S,Dh] bf16 (pre-scaled)
    ushort* Kh  = Qh + MD;            // 8 MB  [B,H,S,Dh] bf16
    ushort* Vt  = Kh + MD;            // 8 MB  [B,H,Dh,S] bf16
    ushort* Yh  = Vt + MD;            // 8 MB  [M,D] bf16
    if (ws_size < 48u * 1024u * 1024u) return;

    dim3 blk(256);
    cast_f32_bf16<<<dim3((int)(MD / 4 / 256)), blk, 0, stream>>>(x,  xh,           (int)(MD / 4));
    cast_f32_bf16<<<dim3((int)(WD / 4 / 256)), blk, 0, stream>>>(wq, Wh,           (int)(WD / 4));
    cast_f32_bf16<<<dim3((int)(WD / 4 / 256)), blk, 0, stream>>>(wk, Wh + WD,      (int)(WD / 4));
    cast_f32_bf16<<<dim3((int)(WD / 4 / 256)), blk, 0, stream>>>(wv, Wh + 2 * WD,  (int)(WD / 4));
    cast_f32_bf16<<<dim3((int)(WD / 4 / 256)), blk, 0, stream>>>(wo, Woh,          (int)(WD / 4));

    gemm_bf16<<<dim3(24, 32), blk, 0, stream>>>(xh, Wh, Qh, Kh, Vt, nullptr, nullptr, 0);
    attn_mfma<<<dim3(512), blk, 0, stream>>>(Qh, Kh, Vt, Yh);
    gemm_bf16<<<dim3(8, 32), blk, 0, stream>>>(Yh, Woh, nullptr, nullptr, nullptr, out, bo, 1);
}

// Round 5
// 224.593 us; speedup vs baseline: 1.7406x; 1.1733x over previous
//
#include <hip/hip_runtime.h>
#include <math.h>

#define B_DIM 2
#define S_DIM 2048
#define D_DIM 1024
#define H_NUM 16
#define DH    64
#define M_DIM (B_DIM * S_DIM) /* 4096 */

typedef __attribute__((ext_vector_type(8))) short short8;
typedef __attribute__((ext_vector_type(4))) short short4v;
typedef __attribute__((ext_vector_type(4))) float float4v;
typedef __attribute__((ext_vector_type(4))) unsigned short ushort4v;
typedef unsigned short ushort;

static __device__ __forceinline__ ushort f2bf(float f) {
    unsigned u = __float_as_uint(f);
    u += 0x7fffu + ((u >> 16) & 1u);
    return (ushort)(u >> 16);
}

static __device__ __forceinline__ float fexp2(float x) {
#if __has_builtin(__builtin_amdgcn_exp2f)
    return __builtin_amdgcn_exp2f(x);
#else
    return exp2f(x);
#endif
}

// pack 2 f32 -> bf16 pair in one u32, lo half = first arg (memory order)
static __device__ __forceinline__ unsigned pack_bf16(float lo, float hi) {
    return (unsigned)f2bf(lo) | ((unsigned)f2bf(hi) << 16);
}

static __device__ __forceinline__ void gload_lds16(const void* g, void* l) {
    __builtin_amdgcn_global_load_lds(
        (const __attribute__((address_space(1))) void*)g,
        (__attribute__((address_space(3))) void*)l, 16, 0, 0);
}

// ---------------------------------------------------------------------------
// Fused fp32 -> bf16 cast of ALL five tensors in one launch.
// dst layout (contiguous in ws): xh[4M] | wq[1M] | wk[1M] | wv[1M] | wo[1M]
// ---------------------------------------------------------------------------
__global__ __launch_bounds__(256)
void cast_all(const float* __restrict__ x,  const float* __restrict__ wq,
              const float* __restrict__ wk, const float* __restrict__ wv,
              const float* __restrict__ wo, ushort* __restrict__ dst)
{
    const int i = blockIdx.x * 256 + threadIdx.x;   // 0 .. 2M-1 (float4 units)
    const float4* s;
    int off;
    if      (i < 1048576) { s = (const float4*)x;  off = 0;       }
    else if (i < 1310720) { s = (const float4*)wq; off = 1048576; }
    else if (i < 1572864) { s = (const float4*)wk; off = 1310720; }
    else if (i < 1835008) { s = (const float4*)wv; off = 1572864; }
    else                  { s = (const float4*)wo; off = 1835008; }
    const float4 v = s[i - off];
    ushort4v o;
    o[0] = f2bf(v.x); o[1] = f2bf(v.y); o[2] = f2bf(v.z); o[3] = f2bf(v.w);
    ((ushort4v*)dst)[i] = o;
}

// ---------------------------------------------------------------------------
// bf16 MFMA GEMM, m97 structure: 128x128 tile, BK=32, global_load_lds w=16,
// 4 waves in 2x2, each wave 64x64 via 4x4 grid of 16x16x32 MFMAs.
// A:[M=4096, K=1024] bf16 row-major. B:[N, K=1024] bf16 row-major.
// mode 0 (N=3072, fused QKV): n>>10 selects dst: 0->Qh [B,H,S,Dh]
//        (PRE-SCALED by 0.125*log2e for base-2 online softmax),
//        1->Kh [B,H,S,Dh], 2->Vt [B,H,Dh,S]; all bf16.
// mode 1 (N=1024, out proj): fp32 out[m*1024+n] = acc + bias[n].
// ---------------------------------------------------------------------------
__global__ __launch_bounds__(256)
void gemm_bf16(const ushort* __restrict__ A, const ushort* __restrict__ B,
               ushort* __restrict__ Qh, ushort* __restrict__ Kh,
               ushort* __restrict__ Vt, float* __restrict__ Of,
               const float* __restrict__ bias, int mode)
{
    __shared__ ushort Asm[128 * 32];   // [row][k], 64B rows, lane-order (no pad!)
    __shared__ ushort Bsm[128 * 32];

    const int K  = 1024;
    const int n0 = blockIdx.x * 128;
    const int m0 = blockIdx.y * 128;
    const int t    = threadIdx.x;
    const int w    = t >> 6;
    const int lane = t & 63;
    const int n    = lane & 15;
    const int quad = lane >> 4;
    const int wm = w >> 1, wn = w & 1;

    const int srow = w * 32 + (lane >> 2);
    const int skel = (lane & 3) * 8;

    float4v acc[4][4];
#pragma unroll
    for (int mt = 0; mt < 4; ++mt)
#pragma unroll
        for (int nt = 0; nt < 4; ++nt) acc[mt][nt] = (float4v){0.f, 0.f, 0.f, 0.f};

    for (int kt = 0; kt < K; kt += 32) {
#pragma unroll
        for (int i = 0; i < 2; ++i) {
            gload_lds16(&A[(size_t)(m0 + srow + i * 16) * K + kt + skel],
                        &Asm[(w * 2 + i) * 512]);
            gload_lds16(&B[(size_t)(n0 + srow + i * 16) * K + kt + skel],
                        &Bsm[(w * 2 + i) * 512]);
        }
        __syncthreads();

        short8 af[4], bfr[4];
#pragma unroll
        for (int mt = 0; mt < 4; ++mt)
            af[mt] = *(const short8*)&Asm[(wm * 64 + mt * 16 + n) * 32 + quad * 8];
#pragma unroll
        for (int nt = 0; nt < 4; ++nt)
            bfr[nt] = *(const short8*)&Bsm[(wn * 64 + nt * 16 + n) * 32 + quad * 8];

#pragma unroll
        for (int mt = 0; mt < 4; ++mt)
#pragma unroll
            for (int nt = 0; nt < 4; ++nt)
                acc[mt][nt] = __builtin_amdgcn_mfma_f32_16x16x32_bf16(
                    af[mt], bfr[nt], acc[mt][nt], 0, 0, 0);
        __syncthreads();
    }

    if (mode == 0) {
        const int wid = n0 >> 10;           // 0=Q 1=K 2=V (constant per block)
        ushort* dstQK = (wid == 0) ? Qh : Kh;
        const float qs = (wid == 0) ? 0.1803368801f : 1.0f;  // 0.125*log2(e)
#pragma unroll
        for (int mt = 0; mt < 4; ++mt) {
            const int m = m0 + wm * 64 + mt * 16 + quad * 4;   // +r
            const int b = m >> 11, s = m & (S_DIM - 1);
#pragma unroll
            for (int nt = 0; nt < 4; ++nt) {
                const int ng = (n0 & 1023) + wn * 64 + nt * 16 + n;
                const int h = ng >> 6, d = ng & 63;
                const int bh = b * H_NUM + h;
                if (wid < 2) {
#pragma unroll
                    for (int r = 0; r < 4; ++r)
                        dstQK[(((size_t)bh * S_DIM + s + r) << 6) + d] =
                            f2bf(acc[mt][nt][r] * qs);
                } else {
                    ushort4v p;
#pragma unroll
                    for (int r = 0; r < 4; ++r) p[r] = f2bf(acc[mt][nt][r]);
                    *(ushort4v*)&Vt[(((size_t)bh * DH + d) << 11) + s] = p;
                }
            }
        }
    } else {
#pragma unroll
        for (int mt = 0; mt < 4; ++mt) {
            const int m = m0 + wm * 64 + mt * 16 + quad * 4;
#pragma unroll
            for (int nt = 0; nt < 4; ++nt) {
                const int ng = n0 + wn * 64 + nt * 16 + n;
                const float bv = bias[ng];
#pragma unroll
                for (int r = 0; r < 4; ++r)
                    Of[(size_t)(m + r) * D_DIM + ng] = acc[mt][nt][r] + bv;
            }
        }
    }
}

// ---------------------------------------------------------------------------
// MFMA flash attention, swapped-QK^T, fully LOCAL P->PV handoff.
// S^T = mfma(K, Q): lane (n, quad) holds S[q=n][key = ct*16 + quad*4 + r].
// PV uses the free k-slot->key remap  slot q*8+e <-> key 32kc+16(e>>2)+4q+(e&3)
// (legal: A and B use the SAME map, so the MFMA dot product is unchanged).
// Under this map the PV A-fragment is the lane's OWN pv[] values -- no
// cross-lane redistribution at all (rounds 3/4 failed on the bpermute's
// source-side operand selection; this removes the bpermutes entirely).
// V B-fragment: two ds_read_b64 at cols 32kc+4q and 32kc+16+4q (swizzled).
// Defer-max (THR=8, base-2); Q pre-scaled by 0.125*log2e.
// ---------------------------------------------------------------------------
__global__ __launch_bounds__(256)
void attn_mfma(const ushort* __restrict__ Qh, const ushort* __restrict__ Kh,
               const ushort* __restrict__ Vt, ushort* __restrict__ Yh)
{
    __shared__ ushort Ksm[2][64 * 64];   // [buf][key 64][d 64] granule-swizzled
    __shared__ ushort Vsm[2][64 * 64];   // [buf][d 64][key 64] granule-swizzled

    const int w    = threadIdx.x >> 6;
    const int lane = threadIdx.x & 63;
    const int n    = lane & 15;
    const int quad = lane >> 4;

    const int wave_id = blockIdx.x * 4 + w;
    const int bh    = wave_id >> 6;          // all 4 waves of a block: same bh
    const int qbase = (wave_id & 63) * 32;
    const int b     = bh >> 4;
    const int h     = bh & (H_NUM - 1);

    const ushort* Qb = Qh + (((size_t)bh * S_DIM) << 6);
    const ushort* Kb = Kh + (((size_t)bh * S_DIM) << 6);
    const ushort* Vb = Vt + (((size_t)bh * DH) << 11);

    // staging: lane l covers row sub-index l>>3, 16B granule (l&7), source
    // granule pre-swizzled (gload_lds dst must stay linear).
    const int l8 = lane >> 3;
    const int sg = (lane & 7) ^ l8;

    short8 qa[2][2];   // B-frag: lane holds Q[q = mt*16+n][d = kc*32+quad*8 ..]
#pragma unroll
    for (int mt = 0; mt < 2; ++mt)
#pragma unroll
        for (int kc = 0; kc < 2; ++kc)
            qa[mt][kc] = *(const short8*)&Qb[((size_t)(qbase + mt * 16 + n) << 6) + kc * 32 + quad * 8];

    float4v O[2][4];           // O[mt][nt][r]: q = mt*16+quad*4+r, d = nt*16+n
    float   mrow[2], lrow[2];  // per-lane: q = mt*16 + n (uniform over quads)
#pragma unroll
    for (int mt = 0; mt < 2; ++mt) {
#pragma unroll
        for (int nt = 0; nt < 4; ++nt) O[mt][nt] = (float4v){0.f, 0.f, 0.f, 0.f};
        mrow[mt] = -1e30f; lrow[mt] = 0.f;
    }

    // K fragment-read offsets (ushort units): logical granule g at row rr is
    // stored at physical g ^ (rr&7); rr&7 == n&7 for rr = xt*16 + n.
    const int fswz[2] = { ((0 * 4 + quad) ^ (n & 7)) * 8,
                          ((1 * 4 + quad) ^ (n & 7)) * 8 };
    // V b64 read offsets for the slot-key remap: for kc, cc: logical granule
    // 4kc + 2cc + (quad>>1), half (quad&1); physical = logical ^ (n&7).
    const int h4 = (quad & 1) * 4;
    const int q2 = quad >> 1;
    int vswz[2][2];
#pragma unroll
    for (int kc = 0; kc < 2; ++kc)
#pragma unroll
        for (int cc = 0; cc < 2; ++cc)
            vswz[kc][cc] = (((4 * kc + 2 * cc + q2) ^ (n & 7)) << 3) + h4;

    // prologue: stage tile 0 into buffer 0
#pragma unroll
    for (int i = 0; i < 2; ++i) {
        gload_lds16(&Kb[(size_t)(w * 16 + i * 8 + l8) * 64 + sg * 8],
                    &Ksm[0][(w * 16 + i * 8) * 64]);
        gload_lds16(&Vb[(size_t)(w * 16 + i * 8 + l8) * 2048 + sg * 8],
                    &Vsm[0][(w * 16 + i * 8) * 64]);
    }

    for (int kb = 0; kb < S_DIM / 64; ++kb) {
        __syncthreads();   // stage(kb) complete; buf cur^1 free for overwrite
        const int cur = kb & 1;
        if (kb + 1 < S_DIM / 64) {
            const int key1 = (kb + 1) * 64;
            const int nxt  = cur ^ 1;
#pragma unroll
            for (int i = 0; i < 2; ++i) {
                gload_lds16(&Kb[(size_t)(key1 + w * 16 + i * 8 + l8) * 64 + sg * 8],
                            &Ksm[nxt][(w * 16 + i * 8) * 64]);
                gload_lds16(&Vb[(size_t)(w * 16 + i * 8 + l8) * 2048 + key1 + sg * 8],
                            &Vsm[nxt][(w * 16 + i * 8) * 64]);
            }
        }

        // A-frag: lane holds K[key = ct*16+n][d = kc*32+quad*8 ..]
        short8 kf[4][2];
#pragma unroll
        for (int ct = 0; ct < 4; ++ct)
#pragma unroll
            for (int kc = 0; kc < 2; ++kc)
                kf[ct][kc] = *(const short8*)&Ksm[cur][(ct * 16 + n) * 64 + fswz[kc]];

        // S^T[key][q]: s[mt][ct][r] = S[q = mt*16+n][key = ct*16+quad*4+r]
        float4v s[2][4];
#pragma unroll
        for (int mt = 0; mt < 2; ++mt)
#pragma unroll
            for (int ct = 0; ct < 4; ++ct) {
                float4v a = (float4v){0.f, 0.f, 0.f, 0.f};
                a = __builtin_amdgcn_mfma_f32_16x16x32_bf16(kf[ct][0], qa[mt][0], a, 0, 0, 0);
                a = __builtin_amdgcn_mfma_f32_16x16x32_bf16(kf[ct][1], qa[mt][1], a, 0, 0, 0);
                s[mt][ct] = a;
            }

        // B-frag under remap: slot q*8+e holds V[key = 32kc+16(e>>2)+4q+(e&3)]
        // [d = nt*16+n]; two b64 reads concatenated.
        short8 vf[4][2];
#pragma unroll
        for (int nt = 0; nt < 4; ++nt) {
            const int rb = (nt * 16 + n) * 64;
#pragma unroll
            for (int kc = 0; kc < 2; ++kc) {
                const short4v g0 = *(const short4v*)&Vsm[cur][rb + vswz[kc][0]];
                const short4v g1 = *(const short4v*)&Vsm[cur][rb + vswz[kc][1]];
                vf[nt][kc] = __builtin_shufflevector(g0, g1, 0, 1, 2, 3, 4, 5, 6, 7);
            }
        }

#pragma unroll
        for (int mt = 0; mt < 2; ++mt) {
            // tile max for q = mt*16+n (my 16 keys, then across quads)
            float lm = s[mt][0][0];
#pragma unroll
            for (int ct = 0; ct < 4; ++ct)
#pragma unroll
                for (int r = 0; r < 4; ++r)
                    lm = fmaxf(lm, s[mt][ct][r]);
            lm = fmaxf(lm, __shfl_xor(lm, 16, 64));
            lm = fmaxf(lm, __shfl_xor(lm, 32, 64));

            const bool ev = lm > mrow[mt] + 8.0f;   // defer-max threshold
            if (__any(ev)) {
                const float mnew  = ev ? lm : mrow[mt];
                const float alpha = fexp2(mrow[mt] - mnew);  // 1.0 when !ev
                mrow[mt] = mnew;
                lrow[mt] *= alpha;
                const int ai = __float_as_int(alpha);
                float av[4];
#pragma unroll
                for (int r = 0; r < 4; ++r)
                    av[r] = __int_as_float(
                        __builtin_amdgcn_ds_bpermute(4 * (quad * 4 + r), ai));
#pragma unroll
                for (int nt = 0; nt < 4; ++nt)
#pragma unroll
                    for (int r = 0; r < 4; ++r) O[mt][nt][r] *= av[r];
            }

            // P = 2^(s - m); l as local partial (reduced once at the end)
            float pv[4][4];
            float lsum = 0.f;
#pragma unroll
            for (int ct = 0; ct < 4; ++ct)
#pragma unroll
                for (int r = 0; r < 4; ++r) {
                    const float p = fexp2(s[mt][ct][r] - mrow[mt]);
                    pv[ct][r] = p;
                    lsum += p;
                }
            lrow[mt] += lsum;

            // PV A-frag is PURELY LOCAL under the remap:
            // element e of pk[kc] = pv[2kc + (e>>2)][e&3]
            union { unsigned u[4]; short8 s8; } pk[2];
#pragma unroll
            for (int kc = 0; kc < 2; ++kc) {
                pk[kc].u[0] = pack_bf16(pv[2 * kc][0],     pv[2 * kc][1]);
                pk[kc].u[1] = pack_bf16(pv[2 * kc][2],     pv[2 * kc][3]);
                pk[kc].u[2] = pack_bf16(pv[2 * kc + 1][0], pv[2 * kc + 1][1]);
                pk[kc].u[3] = pack_bf16(pv[2 * kc + 1][2], pv[2 * kc + 1][3]);
            }

#pragma unroll
            for (int nt = 0; nt < 4; ++nt) {
                O[mt][nt] = __builtin_amdgcn_mfma_f32_16x16x32_bf16(pk[0].s8, vf[nt][0], O[mt][nt], 0, 0, 0);
                O[mt][nt] = __builtin_amdgcn_mfma_f32_16x16x32_bf16(pk[1].s8, vf[nt][1], O[mt][nt], 0, 0, 0);
            }
        }
    }

#pragma unroll
    for (int mt = 0; mt < 2; ++mt) {
        float ls = lrow[mt];
        ls += __shfl_xor(ls, 16, 64);
        ls += __shfl_xor(ls, 32, 64);
        const float linv = 1.f / ls;            // at lane: q = mt*16 + n
        const int  li = __float_as_int(linv);
        float lv[4];
#pragma unroll
        for (int r = 0; r < 4; ++r)
            lv[r] = __int_as_float(
                __builtin_amdgcn_ds_bpermute(4 * (quad * 4 + r), li));
#pragma unroll
        for (int nt = 0; nt < 4; ++nt)
#pragma unroll
            for (int r = 0; r < 4; ++r) {
                const int q = qbase + mt * 16 + quad * 4 + r;
                Yh[((size_t)(b * S_DIM + q) << 10) + h * DH + nt * 16 + n] =
                    f2bf(O[mt][nt][r] * lv[r]);
            }
    }
}

// ---------------------------------------------------------------------------
extern "C" void kernel_launch(void* const* d_in, const int* in_sizes, int n_in,
                              void* d_out, int out_size, void* d_ws, size_t ws_size,
                              hipStream_t stream)
{
    const float* x  = (const float*)d_in[0];
    const float* wq = (const float*)d_in[1];
    const float* wk = (const float*)d_in[2];
    const float* wv = (const float*)d_in[3];
    const float* wo = (const float*)d_in[4];
    const float* bo = (const float*)d_in[5];
    float* out = (float*)d_out;

    const size_t MD = (size_t)M_DIM * D_DIM;      // 4M elements
    const size_t WD = (size_t)D_DIM * D_DIM;      // 1M elements
    ushort* xh  = (ushort*)d_ws;      // 8 MB  [M,K] bf16
    ushort* Wh  = xh + MD;            // 6 MB  [3072,1024] bf16 (wq|wk|wv)
    ushort* Woh = Wh + 3 * WD;        // 2 MB  [1024,1024] bf16
    ushort* Qh  = Woh + WD;           // 8 MB  [B,H,S,Dh] bf16 (pre-scaled)
    ushort* Kh  = Qh + MD;            // 8 MB  [B,H,S,Dh] bf16
    ushort* Vt  = Kh + MD;            // 8 MB  [B,H,Dh,S] bf16
    ushort* Yh  = Vt + MD;            // 8 MB  [M,D] bf16
    if (ws_size < 48u * 1024u * 1024u) return;

    dim3 blk(256);
    cast_all<<<dim3(8192), blk, 0, stream>>>(x, wq, wk, wv, wo, xh);

    gemm_bf16<<<dim3(24, 32), blk, 0, stream>>>(xh, Wh, Qh, Kh, Vt, nullptr, nullptr, 0);
    attn_mfma<<<dim3(512), blk, 0, stream>>>(Qh, Kh, Vt, Yh);
    gemm_bf16<<<dim3(8, 32), blk, 0, stream>>>(Yh, Woh, nullptr, nullptr, nullptr, out, bo, 1);
}